// Round 4
// baseline (457.178 us; speedup 1.0000x reference)
//
#include <hip/hip_runtime.h>
#include <hip/hip_bf16.h>
#include <hip/hip_cooperative_groups.h>

namespace cg = cooperative_groups;

#define B_SZ 4096
#define DZ   512
#define H_SZ 2048
#define DY   10

typedef __attribute__((ext_vector_type(8))) __bf16 bf16x8;
typedef __attribute__((ext_vector_type(4))) float  f32x4;
typedef __attribute__((ext_vector_type(8))) unsigned short us8;

__device__ inline unsigned short f2bf(float f) {
    unsigned u = __float_as_uint(f);
    u += 0x7fffu + ((u >> 16) & 1u);   // round-to-nearest-even
    return (unsigned short)(u >> 16);
}
__device__ inline float bf2f(unsigned short s) {
    return __uint_as_float(((unsigned)s) << 16);
}

// ===========================================================================
// Shared LDS type for prep phases
// ===========================================================================
union SqSmem {
    struct { unsigned short A[64 * 64]; unsigned short B[64 * 64]; } s; // 16 KB
    float epi[64 * 68];                                                 // 17.4 KB
};

// ===========================================================================
// dev_init: x -> bf16 ; W1 -> bf16 ; y = b2 ; blocks 0..63: E0 = dt*A + hi/hiT
// ===========================================================================
__device__ inline void dev_init(int b, int t,
    const float* __restrict__ Ain, const float* __restrict__ x,
    const float* __restrict__ W1, const float* __restrict__ b2,
    float* __restrict__ E, unsigned short* __restrict__ hi,
    unsigned short* __restrict__ hiT, unsigned short* __restrict__ x_bf,
    unsigned short* __restrict__ w1_bf, float* __restrict__ y, SqSmem& sm) {
    const float dt = 1.0f / 64.0f;
    const float4* x4 = (const float4*)x;
#pragma unroll
    for (int i = 0; i < 4; ++i) {
        int id = b * 1024 + i * 256 + t;
        float4 v0 = x4[(size_t)id * 2], v1 = x4[(size_t)id * 2 + 1];
        us8 o;
        o[0] = f2bf(v0.x); o[1] = f2bf(v0.y); o[2] = f2bf(v0.z); o[3] = f2bf(v0.w);
        o[4] = f2bf(v1.x); o[5] = f2bf(v1.y); o[6] = f2bf(v1.z); o[7] = f2bf(v1.w);
        *(us8*)&x_bf[(size_t)id * 8] = o;
    }
    const float4* w4 = (const float4*)W1;
#pragma unroll
    for (int i = 0; i < 2; ++i) {
        int id = b * 512 + i * 256 + t;
        float4 v0 = w4[(size_t)id * 2], v1 = w4[(size_t)id * 2 + 1];
        us8 o;
        o[0] = f2bf(v0.x); o[1] = f2bf(v0.y); o[2] = f2bf(v0.z); o[3] = f2bf(v0.w);
        o[4] = f2bf(v1.x); o[5] = f2bf(v1.y); o[6] = f2bf(v1.z); o[7] = f2bf(v1.w);
        *(us8*)&w1_bf[(size_t)id * 8] = o;
    }
    if (t < 160) { int id = b * 160 + t; y[id] = b2[id % 10]; }

    if (b < 64) {
        const int m0 = (b >> 3) * 64, n0 = (b & 7) * 64;
        const int r = t >> 2, cq = t & 3;
        float vals[16];
#pragma unroll
        for (int u = 0; u < 4; ++u) {
            float4 a = *(const float4*)&Ain[(size_t)(m0 + r) * 512 + n0 + cq * 16 + u * 4];
            vals[u * 4 + 0] = dt * a.x; vals[u * 4 + 1] = dt * a.y;
            vals[u * 4 + 2] = dt * a.z; vals[u * 4 + 3] = dt * a.w;
        }
#pragma unroll
        for (int u = 0; u < 4; ++u)
            *(float4*)&E[(size_t)(m0 + r) * 512 + n0 + cq * 16 + u * 4] =
                make_float4(vals[u * 4], vals[u * 4 + 1], vals[u * 4 + 2], vals[u * 4 + 3]);
        us8 h0, h1;
#pragma unroll
        for (int j = 0; j < 8; ++j) { h0[j] = f2bf(vals[j]); h1[j] = f2bf(vals[8 + j]); }
        *(us8*)&hi[(size_t)(m0 + r) * 512 + n0 + cq * 16]     = h0;
        *(us8*)&hi[(size_t)(m0 + r) * 512 + n0 + cq * 16 + 8] = h1;
#pragma unroll
        for (int j = 0; j < 16; ++j) sm.epi[r * 68 + cq * 16 + j] = vals[j];
        __syncthreads();
        const int cf = t >> 2, rq = t & 3;
        us8 o0, o1;
#pragma unroll
        for (int i = 0; i < 8; ++i) {
            o0[i] = f2bf(sm.epi[(rq * 16 + i) * 68 + cf]);
            o1[i] = f2bf(sm.epi[(rq * 16 + 8 + i) * 68 + cf]);
        }
        *(us8*)&hiT[(size_t)(n0 + cf) * 512 + m0 + rq * 16]     = o0;
        *(us8*)&hiT[(size_t)(n0 + cf) * 512 + m0 + rq * 16 + 8] = o1;
    }
}

// ===========================================================================
// gemm64_mfma: 64x64 tile of A*B^T (both operands row-major bf16, K=512),
// result dumped to sm.epi[r*68+c].
// ===========================================================================
__device__ inline void gemm64_mfma(const unsigned short* __restrict__ Arows,
                                   const unsigned short* __restrict__ Brows,
                                   int m0, int n0, int t, SqSmem& sm) {
    const int lane = t & 63, w = t >> 6, quad = lane >> 4, l16 = lane & 15;
    const int wm = (w & 1) * 32, wn = (w >> 1) * 32;
    f32x4 acc[2][2];
#pragma unroll
    for (int i = 0; i < 2; ++i)
#pragma unroll
        for (int j = 0; j < 2; ++j) acc[i][j] = (f32x4){0.f, 0.f, 0.f, 0.f};
    for (int kt = 0; kt < 8; ++kt) {
#pragma unroll
        for (int c = 0; c < 2; ++c) {
            int idx = c * 256 + t, row = idx >> 3, cc = idx & 7;
            int ccs = cc ^ (row & 7);
            *(us8*)&sm.s.A[row * 64 + ccs * 8] =
                *(const us8*)&Arows[(size_t)(m0 + row) * 512 + kt * 64 + cc * 8];
            *(us8*)&sm.s.B[row * 64 + ccs * 8] =
                *(const us8*)&Brows[(size_t)(n0 + row) * 512 + kt * 64 + cc * 8];
        }
        __syncthreads();
#pragma unroll
        for (int ks = 0; ks < 2; ++ks) {
            bf16x8 af[2], bfr[2];
#pragma unroll
            for (int i = 0; i < 2; ++i) {
                int ra = wm + i * 16 + l16, ca = (ks * 4 + quad) ^ (ra & 7);
                af[i] = *(const bf16x8*)&sm.s.A[ra * 64 + ca * 8];
                int rb = wn + i * 16 + l16, cb = (ks * 4 + quad) ^ (rb & 7);
                bfr[i] = *(const bf16x8*)&sm.s.B[rb * 64 + cb * 8];
            }
#pragma unroll
            for (int i = 0; i < 2; ++i)
#pragma unroll
                for (int j = 0; j < 2; ++j)
                    acc[i][j] = __builtin_amdgcn_mfma_f32_16x16x32_bf16(
                        af[i], bfr[j], acc[i][j], 0, 0, 0);
        }
        __syncthreads();
    }
#pragma unroll
    for (int i = 0; i < 2; ++i)
#pragma unroll
        for (int j = 0; j < 2; ++j)
#pragma unroll
            for (int rr = 0; rr < 4; ++rr)
                sm.epi[(wm + i * 16 + quad * 4 + rr) * 68 + wn + j * 16 + l16] =
                    acc[i][j][rr];
    __syncthreads();
}

// ===========================================================================
// dev_sq: E' = 2E + E*E (blocks 0..63 active)
// ===========================================================================
__device__ inline void dev_sq(int b, int t,
    const float* __restrict__ E, const unsigned short* __restrict__ hi,
    const unsigned short* __restrict__ hiT, float* __restrict__ Eo,
    unsigned short* __restrict__ hio, unsigned short* __restrict__ hiTo,
    SqSmem& sm) {
    if (b >= 64) return;
    const int m0 = (b >> 3) * 64, n0 = (b & 7) * 64;
    gemm64_mfma(hi, hiT, m0, n0, t, sm);
    {
        const int r = t >> 2, cq = t & 3;
        float e2[16];
#pragma unroll
        for (int u = 0; u < 4; ++u) {
            float4 ev = *(const float4*)&E[(size_t)(m0 + r) * 512 + n0 + cq * 16 + u * 4];
            e2[u * 4 + 0] = 2.f * ev.x + sm.epi[r * 68 + cq * 16 + u * 4 + 0];
            e2[u * 4 + 1] = 2.f * ev.y + sm.epi[r * 68 + cq * 16 + u * 4 + 1];
            e2[u * 4 + 2] = 2.f * ev.z + sm.epi[r * 68 + cq * 16 + u * 4 + 2];
            e2[u * 4 + 3] = 2.f * ev.w + sm.epi[r * 68 + cq * 16 + u * 4 + 3];
        }
#pragma unroll
        for (int u = 0; u < 4; ++u)
            *(float4*)&Eo[(size_t)(m0 + r) * 512 + n0 + cq * 16 + u * 4] =
                make_float4(e2[u * 4], e2[u * 4 + 1], e2[u * 4 + 2], e2[u * 4 + 3]);
        us8 h0, h1;
#pragma unroll
        for (int j = 0; j < 8; ++j) { h0[j] = f2bf(e2[j]); h1[j] = f2bf(e2[8 + j]); }
        *(us8*)&hio[(size_t)(m0 + r) * 512 + n0 + cq * 16]     = h0;
        *(us8*)&hio[(size_t)(m0 + r) * 512 + n0 + cq * 16 + 8] = h1;
        __syncthreads();
#pragma unroll
        for (int j = 0; j < 16; ++j) sm.epi[r * 68 + cq * 16 + j] = e2[j];
    }
    __syncthreads();
    {
        const int cf = t >> 2, rq = t & 3;
        us8 o0, o1;
#pragma unroll
        for (int i = 0; i < 8; ++i) {
            o0[i] = f2bf(sm.epi[(rq * 16 + i) * 68 + cf]);
            o1[i] = f2bf(sm.epi[(rq * 16 + 8 + i) * 68 + cf]);
        }
        *(us8*)&hiTo[(size_t)(n0 + cf) * 512 + m0 + rq * 16]     = o0;
        *(us8*)&hiTo[(size_t)(n0 + cf) * 512 + m0 + rq * 16 + 8] = o1;
    }
}

// ===========================================================================
// dev_fold: w1f = bf16(W1 + W1_bf * E6)   (all 256 blocks)
// ===========================================================================
__device__ inline void dev_fold(int b, int t,
    const unsigned short* __restrict__ w1_bf,
    const unsigned short* __restrict__ hiT, const float* __restrict__ W1,
    unsigned short* __restrict__ w1f, SqSmem& sm) {
    const int m0 = (b >> 3) * 64, n0 = (b & 7) * 64;
    gemm64_mfma(w1_bf, hiT, m0, n0, t, sm);
    const int r = t >> 2, cq = t & 3;
    float e2[16];
#pragma unroll
    for (int u = 0; u < 4; ++u) {
        float4 wv = *(const float4*)&W1[(size_t)(m0 + r) * 512 + n0 + cq * 16 + u * 4];
        e2[u * 4 + 0] = wv.x + sm.epi[r * 68 + cq * 16 + u * 4 + 0];
        e2[u * 4 + 1] = wv.y + sm.epi[r * 68 + cq * 16 + u * 4 + 1];
        e2[u * 4 + 2] = wv.z + sm.epi[r * 68 + cq * 16 + u * 4 + 2];
        e2[u * 4 + 3] = wv.w + sm.epi[r * 68 + cq * 16 + u * 4 + 3];
    }
    us8 h0, h1;
#pragma unroll
    for (int j = 0; j < 8; ++j) { h0[j] = f2bf(e2[j]); h1[j] = f2bf(e2[8 + j]); }
    *(us8*)&w1f[(size_t)(m0 + r) * 512 + n0 + cq * 16]     = h0;
    *(us8*)&w1f[(size_t)(m0 + r) * 512 + n0 + cq * 16 + 8] = h1;
}

// ===========================================================================
// Fused cooperative prep (256 blocks x 256 thr, 1 block/CU co-resident)
// ===========================================================================
__global__ __launch_bounds__(256) void coop_prep(
    const float* __restrict__ Ain, const float* __restrict__ x,
    const float* __restrict__ W1, const float* __restrict__ b2,
    float* __restrict__ Ea, unsigned short* __restrict__ hiA,
    unsigned short* __restrict__ hiTA, float* __restrict__ Eb,
    unsigned short* __restrict__ hiB, unsigned short* __restrict__ hiTB,
    unsigned short* __restrict__ x_bf, unsigned short* __restrict__ w1_bf,
    unsigned short* __restrict__ w1f, float* __restrict__ y) {
    cg::grid_group grid = cg::this_grid();
    __shared__ SqSmem sm;
    const int b = blockIdx.x, t = threadIdx.x;
    dev_init(b, t, Ain, x, W1, b2, Ea, hiA, hiTA, x_bf, w1_bf, y, sm);
    grid.sync();
    dev_sq(b, t, Ea, hiA, hiTA, Eb, hiB, hiTB, sm); grid.sync();
    dev_sq(b, t, Eb, hiB, hiTB, Ea, hiA, hiTA, sm); grid.sync();
    dev_sq(b, t, Ea, hiA, hiTA, Eb, hiB, hiTB, sm); grid.sync();
    dev_sq(b, t, Eb, hiB, hiTB, Ea, hiA, hiTA, sm); grid.sync();
    dev_sq(b, t, Ea, hiA, hiTA, Eb, hiB, hiTB, sm); grid.sync();
    dev_sq(b, t, Eb, hiB, hiTB, Ea, hiA, hiTA, sm); grid.sync();
    dev_fold(b, t, w1_bf, hiTA, W1, w1f, sm);
}

// ===========================================================================
// Fallback standalone kernels (proven round-3 path)
// ===========================================================================
__global__ __launch_bounds__(256) void k_init(
    const float* __restrict__ Ain, const float* __restrict__ x,
    const float* __restrict__ W1, const float* __restrict__ b2,
    float* __restrict__ E, unsigned short* __restrict__ hi,
    unsigned short* __restrict__ hiT, unsigned short* __restrict__ x_bf,
    unsigned short* __restrict__ w1_bf, float* __restrict__ y) {
    __shared__ SqSmem sm;
    dev_init(blockIdx.x, threadIdx.x, Ain, x, W1, b2, E, hi, hiT, x_bf, w1_bf, y, sm);
}
__global__ __launch_bounds__(256) void k_sq(
    const float* __restrict__ E, const unsigned short* __restrict__ hi,
    const unsigned short* __restrict__ hiT, float* __restrict__ Eo,
    unsigned short* __restrict__ hio, unsigned short* __restrict__ hiTo) {
    __shared__ SqSmem sm;
    dev_sq(blockIdx.x, threadIdx.x, E, hi, hiT, Eo, hio, hiTo, sm);
}
__global__ __launch_bounds__(256) void k_fold(
    const unsigned short* __restrict__ w1_bf,
    const unsigned short* __restrict__ hiT, const float* __restrict__ W1,
    unsigned short* __restrict__ w1f) {
    __shared__ SqSmem sm;
    dev_fold(blockIdx.x, threadIdx.x, w1_bf, hiT, W1, w1f, sm);
}

// ===========================================================================
// mlp v2: 64x64 tiles, grid (64,32)=2048 blocks, double-buffered LDS,
// one barrier per K-iter. h = relu(x_bf @ w1f^T + b1); y += h @ W2^T.
// ===========================================================================
union MlpSmem {
    unsigned short buf[2][2][64 * 64];                       // 32 KB
    struct { unsigned short h[64 * 66]; float w2[DY * 68]; } e; // 11 KB
};

__global__ __launch_bounds__(256, 5) void mlp_kernel(
    const unsigned short* __restrict__ x_bf,
    const unsigned short* __restrict__ w1f,
    const float* __restrict__ b1, const float* __restrict__ W2,
    float* __restrict__ y) {
    __shared__ MlpSmem sm;
    const int t    = threadIdx.x;
    const int lane = t & 63, w = t >> 6;
    const int quad = lane >> 4, l16 = lane & 15;
    const int wm = (w & 1) * 32, wn = (w >> 1) * 32;
    const int m0g = blockIdx.x * 64, n0g = blockIdx.y * 64;

    // staging chunk ids: this thread loads chunks t and t+256 of A and B tiles
    const int r0 = t >> 3,         c0 = t & 7;
    const int r1 = (t + 256) >> 3, c1 = (t + 256) & 7;
    const int s0 = r0 * 64 + (c0 ^ (r0 & 7)) * 8;
    const int s1 = r1 * 64 + (c1 ^ (r1 & 7)) * 8;

    f32x4 acc[2][2];
#pragma unroll
    for (int i = 0; i < 2; ++i)
#pragma unroll
        for (int j = 0; j < 2; ++j) acc[i][j] = (f32x4){0.f, 0.f, 0.f, 0.f};

    us8 ra0 = *(const us8*)&x_bf[(size_t)(m0g + r0) * 512 + c0 * 8];
    us8 ra1 = *(const us8*)&x_bf[(size_t)(m0g + r1) * 512 + c1 * 8];
    us8 rb0 = *(const us8*)&w1f[(size_t)(n0g + r0) * 512 + c0 * 8];
    us8 rb1 = *(const us8*)&w1f[(size_t)(n0g + r1) * 512 + c1 * 8];
    *(us8*)&sm.buf[0][0][s0] = ra0;
    *(us8*)&sm.buf[0][0][s1] = ra1;
    *(us8*)&sm.buf[0][1][s0] = rb0;
    *(us8*)&sm.buf[0][1][s1] = rb1;
    __syncthreads();

    for (int kt = 0; kt < 8; ++kt) {
        const int cur = kt & 1;
        if (kt < 7) {
            int ko = (kt + 1) * 64;
            ra0 = *(const us8*)&x_bf[(size_t)(m0g + r0) * 512 + ko + c0 * 8];
            ra1 = *(const us8*)&x_bf[(size_t)(m0g + r1) * 512 + ko + c1 * 8];
            rb0 = *(const us8*)&w1f[(size_t)(n0g + r0) * 512 + ko + c0 * 8];
            rb1 = *(const us8*)&w1f[(size_t)(n0g + r1) * 512 + ko + c1 * 8];
        }
#pragma unroll
        for (int ks = 0; ks < 2; ++ks) {
            bf16x8 af[2], bfr[2];
#pragma unroll
            for (int i = 0; i < 2; ++i) {
                int ra = wm + i * 16 + l16, ca = (ks * 4 + quad) ^ (ra & 7);
                af[i] = *(const bf16x8*)&sm.buf[cur][0][ra * 64 + ca * 8];
                int rb = wn + i * 16 + l16, cb = (ks * 4 + quad) ^ (rb & 7);
                bfr[i] = *(const bf16x8*)&sm.buf[cur][1][rb * 64 + cb * 8];
            }
#pragma unroll
            for (int i = 0; i < 2; ++i)
#pragma unroll
                for (int j = 0; j < 2; ++j)
                    acc[i][j] = __builtin_amdgcn_mfma_f32_16x16x32_bf16(
                        af[i], bfr[j], acc[i][j], 0, 0, 0);
        }
        if (kt < 7) {
            *(us8*)&sm.buf[1 - cur][0][s0] = ra0;
            *(us8*)&sm.buf[1 - cur][0][s1] = ra1;
            *(us8*)&sm.buf[1 - cur][1][s0] = rb0;
            *(us8*)&sm.buf[1 - cur][1][s1] = rb1;
        }
        __syncthreads();
    }

    // ---- epilogue: bias + relu -> LDS h (n-major), then y += h @ W2^T ----
    float bias[2];
#pragma unroll
    for (int j = 0; j < 2; ++j) bias[j] = b1[n0g + wn + j * 16 + l16];
#pragma unroll
    for (int i = 0; i < 2; ++i)
#pragma unroll
        for (int j = 0; j < 2; ++j)
#pragma unroll
            for (int r = 0; r < 4; ++r) {
                float h = acc[i][j][r] + bias[j];
                h = h > 0.f ? h : 0.f;
                sm.e.h[(wn + j * 16 + l16) * 66 + (wm + i * 16 + quad * 4 + r)] = f2bf(h);
            }
    for (int i = t; i < DY * 64; i += 256) {
        int d = i >> 6, n = i & 63;
        sm.e.w2[d * 68 + n] = W2[(size_t)d * H_SZ + n0g + n];
    }
    __syncthreads();
    {
        int m = t & 63, g = t >> 6;
        int d0 = (g * 10) >> 2, d1 = ((g + 1) * 10) >> 2;
        for (int d = d0; d < d1; ++d) {
            float s = 0.f;
            const float* wrow = &sm.e.w2[d * 68];
#pragma unroll 4
            for (int n = 0; n < 64; ++n)
                s += bf2f(sm.e.h[n * 66 + m]) * wrow[n];
            atomicAdd(&y[(size_t)(m0g + m) * DY + d], s);
        }
    }
}

// ===========================================================================
extern "C" void kernel_launch(void* const* d_in, const int* in_sizes, int n_in,
                              void* d_out, int out_size, void* d_ws, size_t ws_size,
                              hipStream_t stream) {
    const float* x  = (const float*)d_in[0];
    const float* A  = (const float*)d_in[1];
    const float* W1 = (const float*)d_in[2];
    const float* b1 = (const float*)d_in[3];
    const float* W2 = (const float*)d_in[4];
    const float* b2 = (const float*)d_in[5];
    float* y = (float*)d_out;

    char* ws = (char*)d_ws;
    const size_t MB = 1u << 20;
    float* Ea = (float*)ws;
    float* Eb = (float*)(ws + 1 * MB);
    unsigned short* hiA  = (unsigned short*)(ws + 2 * MB);
    unsigned short* hiTA = (unsigned short*)(ws + 2 * MB + 512 * 1024);
    unsigned short* hiB  = (unsigned short*)(ws + 3 * MB);
    unsigned short* hiTB = (unsigned short*)(ws + 3 * MB + 512 * 1024);
    unsigned short* x_bf  = (unsigned short*)(ws + 4 * MB);  // 4 MB
    unsigned short* w1_bf = (unsigned short*)(ws + 8 * MB);  // 2 MB
    unsigned short* w1f   = (unsigned short*)(ws + 10 * MB); // 2 MB

    void* cargs[] = {(void*)&A, (void*)&x, (void*)&W1, (void*)&b2,
                     (void*)&Ea, (void*)&hiA, (void*)&hiTA,
                     (void*)&Eb, (void*)&hiB, (void*)&hiTB,
                     (void*)&x_bf, (void*)&w1_bf, (void*)&w1f, (void*)&y};
    hipError_t ce = hipLaunchCooperativeKernel((const void*)coop_prep,
                                               dim3(256), dim3(256),
                                               cargs, 0, stream);
    if (ce != hipSuccess) {
        // proven round-3 fallback chain
        k_init<<<256, 256, 0, stream>>>(A, x, W1, b2, Ea, hiA, hiTA, x_bf, w1_bf, y);
        k_sq<<<64, 256, 0, stream>>>(Ea, hiA, hiTA, Eb, hiB, hiTB);
        k_sq<<<64, 256, 0, stream>>>(Eb, hiB, hiTB, Ea, hiA, hiTA);
        k_sq<<<64, 256, 0, stream>>>(Ea, hiA, hiTA, Eb, hiB, hiTB);
        k_sq<<<64, 256, 0, stream>>>(Eb, hiB, hiTB, Ea, hiA, hiTA);
        k_sq<<<64, 256, 0, stream>>>(Ea, hiA, hiTA, Eb, hiB, hiTB);
        k_sq<<<64, 256, 0, stream>>>(Eb, hiB, hiTB, Ea, hiA, hiTA);
        k_fold<<<256, 256, 0, stream>>>(w1_bf, hiTA, W1, w1f);
    }
    mlp_kernel<<<dim3(64, 32), dim3(256), 0, stream>>>(x_bf, w1f, b1, W2, y);
}

// Round 5
// 189.158 us; speedup vs baseline: 2.4169x; 2.4169x over previous
//
#include <hip/hip_runtime.h>
#include <hip/hip_bf16.h>

#define B_SZ 4096
#define DZ   512
#define H_SZ 2048
#define DY   10

// binomial coefficients of (1+u)^64 scaled: c_k = C(64,k)/64^k  (compile-time folded)
#define C2 0.4921875f
#define C3 0.158935546875f
#define C4 0.037872314453125f
#define C5 ((float)(7624512.0/1073741824.0))
#define C6 ((float)(74974368.0/68719476736.0))
#define C7 ((float)(621216192.0/4398046511104.0))
#define C8 ((float)(4426165368.0/281474976710656.0))

typedef __attribute__((ext_vector_type(8))) __bf16 bf16x8;
typedef __attribute__((ext_vector_type(4))) float  f32x4;
typedef __attribute__((ext_vector_type(8))) unsigned short us8;

__device__ inline unsigned short f2bf(float f) {
    unsigned u = __float_as_uint(f);
    u += 0x7fffu + ((u >> 16) & 1u);   // RTNE
    return (unsigned short)(u >> 16);
}
__device__ inline float bf2f(unsigned short s) {
    return __uint_as_float(((unsigned)s) << 16);
}

union SqSmem {
    struct { unsigned short A[64 * 64]; unsigned short B[64 * 64]; } s; // 16 KB
    float epi[64 * 68];                                                 // 17.4 KB
};

// ---------------------------------------------------------------------------
// gemm64_mfma: 64x64 tile of (A-rows)·(B-rows)^T, bf16 K=512, result -> sm.epi
// ---------------------------------------------------------------------------
__device__ inline void gemm64_mfma(const unsigned short* __restrict__ Arows,
                                   const unsigned short* __restrict__ Brows,
                                   int m0, int n0, int t, SqSmem& sm) {
    const int lane = t & 63, w = t >> 6, quad = lane >> 4, l16 = lane & 15;
    const int wm = (w & 1) * 32, wn = (w >> 1) * 32;
    f32x4 acc[2][2];
#pragma unroll
    for (int i = 0; i < 2; ++i)
#pragma unroll
        for (int j = 0; j < 2; ++j) acc[i][j] = (f32x4){0.f, 0.f, 0.f, 0.f};
    for (int kt = 0; kt < 8; ++kt) {
#pragma unroll
        for (int c = 0; c < 2; ++c) {
            int idx = c * 256 + t, row = idx >> 3, cc = idx & 7;
            int ccs = cc ^ (row & 7);
            *(us8*)&sm.s.A[row * 64 + ccs * 8] =
                *(const us8*)&Arows[(size_t)(m0 + row) * 512 + kt * 64 + cc * 8];
            *(us8*)&sm.s.B[row * 64 + ccs * 8] =
                *(const us8*)&Brows[(size_t)(n0 + row) * 512 + kt * 64 + cc * 8];
        }
        __syncthreads();
#pragma unroll
        for (int ks = 0; ks < 2; ++ks) {
            bf16x8 af[2], bfr[2];
#pragma unroll
            for (int i = 0; i < 2; ++i) {
                int ra = wm + i * 16 + l16, ca = (ks * 4 + quad) ^ (ra & 7);
                af[i] = *(const bf16x8*)&sm.s.A[ra * 64 + ca * 8];
                int rb = wn + i * 16 + l16, cb = (ks * 4 + quad) ^ (rb & 7);
                bfr[i] = *(const bf16x8*)&sm.s.B[rb * 64 + cb * 8];
            }
#pragma unroll
            for (int i = 0; i < 2; ++i)
#pragma unroll
                for (int j = 0; j < 2; ++j)
                    acc[i][j] = __builtin_amdgcn_mfma_f32_16x16x32_bf16(
                        af[i], bfr[j], acc[i][j], 0, 0, 0);
        }
        __syncthreads();
    }
#pragma unroll
    for (int i = 0; i < 2; ++i)
#pragma unroll
        for (int j = 0; j < 2; ++j)
#pragma unroll
            for (int rr = 0; rr < 4; ++rr)
                sm.epi[(wm + i * 16 + quad * 4 + rr) * 68 + wn + j * 16 + l16] =
                    acc[i][j][rr];
    __syncthreads();
}

// epi write-out helpers (epi holds 64x64 fp32 tile, row stride 68)
__device__ inline void epi_out_f32(float* __restrict__ dst, int m0, int n0,
                                   int t, SqSmem& sm) {
    const int r = t >> 2, cq = t & 3;
#pragma unroll
    for (int u = 0; u < 4; ++u)
        *(float4*)&dst[(size_t)(m0 + r) * 512 + n0 + cq * 16 + u * 4] =
            make_float4(sm.epi[r * 68 + cq * 16 + u * 4 + 0],
                        sm.epi[r * 68 + cq * 16 + u * 4 + 1],
                        sm.epi[r * 68 + cq * 16 + u * 4 + 2],
                        sm.epi[r * 68 + cq * 16 + u * 4 + 3]);
}
__device__ inline void epi_out_bf(unsigned short* __restrict__ dst, int m0,
                                  int n0, int t, SqSmem& sm) {
    const int r = t >> 2, cq = t & 3;
    us8 h0, h1;
#pragma unroll
    for (int j = 0; j < 8; ++j) {
        h0[j] = f2bf(sm.epi[r * 68 + cq * 16 + j]);
        h1[j] = f2bf(sm.epi[r * 68 + cq * 16 + 8 + j]);
    }
    *(us8*)&dst[(size_t)(m0 + r) * 512 + n0 + cq * 16]     = h0;
    *(us8*)&dst[(size_t)(m0 + r) * 512 + n0 + cq * 16 + 8] = h1;
}
__device__ inline void epi_out_bfT(unsigned short* __restrict__ dst, int m0,
                                   int n0, int t, SqSmem& sm) {
    const int cf = t >> 2, rq = t & 3;
    us8 o0, o1;
#pragma unroll
    for (int i = 0; i < 8; ++i) {
        o0[i] = f2bf(sm.epi[(rq * 16 + i) * 68 + cf]);
        o1[i] = f2bf(sm.epi[(rq * 16 + 8 + i) * 68 + cf]);
    }
    *(us8*)&dst[(size_t)(n0 + cf) * 512 + m0 + rq * 16]     = o0;
    *(us8*)&dst[(size_t)(n0 + cf) * 512 + m0 + rq * 16 + 8] = o1;
}

// ===========================================================================
// K1 (grid 256): conversions + AT_bf + A2 = A·A (blocks 0..63, inline staging)
// ===========================================================================
__global__ __launch_bounds__(256) void k_prep1(
    const float* __restrict__ A, const float* __restrict__ x,
    const float* __restrict__ W1, const float* __restrict__ b2,
    float* __restrict__ A2f, unsigned short* __restrict__ A2_bf,
    unsigned short* __restrict__ A2T_bf, unsigned short* __restrict__ AT_bf,
    unsigned short* __restrict__ x_bf, unsigned short* __restrict__ w1_bf,
    float* __restrict__ y) {
    __shared__ SqSmem sm;
    const int b = blockIdx.x, t = threadIdx.x;

    // ---- conversions (all blocks) ----
    const float4* x4 = (const float4*)x;
#pragma unroll
    for (int i = 0; i < 4; ++i) {
        int id = b * 1024 + i * 256 + t;
        float4 v0 = x4[(size_t)id * 2], v1 = x4[(size_t)id * 2 + 1];
        us8 o;
        o[0] = f2bf(v0.x); o[1] = f2bf(v0.y); o[2] = f2bf(v0.z); o[3] = f2bf(v0.w);
        o[4] = f2bf(v1.x); o[5] = f2bf(v1.y); o[6] = f2bf(v1.z); o[7] = f2bf(v1.w);
        *(us8*)&x_bf[(size_t)id * 8] = o;
    }
    const float4* w4 = (const float4*)W1;
#pragma unroll
    for (int i = 0; i < 2; ++i) {
        int id = b * 512 + i * 256 + t;
        float4 v0 = w4[(size_t)id * 2], v1 = w4[(size_t)id * 2 + 1];
        us8 o;
        o[0] = f2bf(v0.x); o[1] = f2bf(v0.y); o[2] = f2bf(v0.z); o[3] = f2bf(v0.w);
        o[4] = f2bf(v1.x); o[5] = f2bf(v1.y); o[6] = f2bf(v1.z); o[7] = f2bf(v1.w);
        *(us8*)&w1_bf[(size_t)id * 8] = o;
    }
    if (t < 160) { int id = b * 160 + t; y[id] = b2[id % 10]; }

    const int r = t >> 2, cq = t & 3;
    if (b < 64) {
        // ---- A2 = A·A, staging straight from fp32 A ----
        const int m0 = (b >> 3) * 64, n0 = (b & 7) * 64;
        const int lane = t & 63, w = t >> 6, quad = lane >> 4, l16 = lane & 15;
        const int wm = (w & 1) * 32, wn = (w >> 1) * 32;
        f32x4 acc[2][2];
#pragma unroll
        for (int i = 0; i < 2; ++i)
#pragma unroll
            for (int j = 0; j < 2; ++j) acc[i][j] = (f32x4){0.f, 0.f, 0.f, 0.f};
        for (int kt = 0; kt < 8; ++kt) {
            // A-side: row r of m-strip, 16 floats at col cq*16
            float va[16];
#pragma unroll
            for (int u = 0; u < 4; ++u) {
                float4 f = *(const float4*)&A[(size_t)(m0 + r) * 512 + kt * 64 + cq * 16 + u * 4];
                va[u * 4 + 0] = f.x; va[u * 4 + 1] = f.y;
                va[u * 4 + 2] = f.z; va[u * 4 + 3] = f.w;
            }
#pragma unroll
            for (int j2 = 0; j2 < 2; ++j2) {
                us8 h;
#pragma unroll
                for (int j = 0; j < 8; ++j) h[j] = f2bf(va[j2 * 8 + j]);
                int cc = cq * 2 + j2;
                *(us8*)&sm.s.A[r * 64 + (cc ^ (r & 7)) * 8] = h;
            }
            // B-side transposed: k-row (kt*64+r), cols n0+cq*16.. -> sB[n][k]
#pragma unroll
            for (int u = 0; u < 4; ++u) {
                float4 f = *(const float4*)&A[(size_t)(kt * 64 + r) * 512 + n0 + cq * 16 + u * 4];
                float vv[4] = {f.x, f.y, f.z, f.w};
#pragma unroll
                for (int j = 0; j < 4; ++j) {
                    int n = cq * 16 + u * 4 + j;
                    sm.s.B[n * 64 + ((r >> 3) ^ (n & 7)) * 8 + (r & 7)] = f2bf(vv[j]);
                }
            }
            __syncthreads();
#pragma unroll
            for (int ks = 0; ks < 2; ++ks) {
                bf16x8 af[2], bfr[2];
#pragma unroll
                for (int i = 0; i < 2; ++i) {
                    int ra = wm + i * 16 + l16, ca = (ks * 4 + quad) ^ (ra & 7);
                    af[i] = *(const bf16x8*)&sm.s.A[ra * 64 + ca * 8];
                    int rb = wn + i * 16 + l16, cb = (ks * 4 + quad) ^ (rb & 7);
                    bfr[i] = *(const bf16x8*)&sm.s.B[rb * 64 + cb * 8];
                }
#pragma unroll
                for (int i = 0; i < 2; ++i)
#pragma unroll
                    for (int j = 0; j < 2; ++j)
                        acc[i][j] = __builtin_amdgcn_mfma_f32_16x16x32_bf16(
                            af[i], bfr[j], acc[i][j], 0, 0, 0);
            }
            __syncthreads();
        }
#pragma unroll
        for (int i = 0; i < 2; ++i)
#pragma unroll
            for (int j = 0; j < 2; ++j)
#pragma unroll
                for (int rr = 0; rr < 4; ++rr)
                    sm.epi[(wm + i * 16 + quad * 4 + rr) * 68 + wn + j * 16 + l16] =
                        acc[i][j][rr];
        __syncthreads();
        epi_out_f32(A2f, m0, n0, t, sm);
        epi_out_bf(A2_bf, m0, n0, t, sm);
        epi_out_bfT(A2T_bf, m0, n0, t, sm);
    } else if (b < 128) {
        // ---- AT_bf tile via LDS transpose ----
        const int bb = b - 64, m0 = (bb >> 3) * 64, n0 = (bb & 7) * 64;
#pragma unroll
        for (int u = 0; u < 4; ++u) {
            float4 f = *(const float4*)&A[(size_t)(m0 + r) * 512 + n0 + cq * 16 + u * 4];
            sm.epi[r * 68 + cq * 16 + u * 4 + 0] = f.x;
            sm.epi[r * 68 + cq * 16 + u * 4 + 1] = f.y;
            sm.epi[r * 68 + cq * 16 + u * 4 + 2] = f.z;
            sm.epi[r * 68 + cq * 16 + u * 4 + 3] = f.w;
        }
        __syncthreads();
        epi_out_bfT(AT_bf, m0, n0, t, sm);
    }
}

// ===========================================================================
// K2 (grid 128): blocks 0..63: A3 = A2·A ; blocks 64..127: A4 = A2·A2
// ===========================================================================
__global__ __launch_bounds__(256) void k_prep2(
    const unsigned short* __restrict__ A2_bf,
    const unsigned short* __restrict__ A2T_bf,
    const unsigned short* __restrict__ AT_bf, float* __restrict__ A3f,
    unsigned short* __restrict__ A3T_bf, float* __restrict__ A4f,
    unsigned short* __restrict__ A4_bf, unsigned short* __restrict__ A4T_bf) {
    __shared__ SqSmem sm;
    const int b = blockIdx.x, t = threadIdx.x, bb = b & 63;
    const int m0 = (bb >> 3) * 64, n0 = (bb & 7) * 64;
    if (b < 64) {
        gemm64_mfma(A2_bf, AT_bf, m0, n0, t, sm);     // A3[m][n]
        epi_out_f32(A3f, m0, n0, t, sm);
        epi_out_bfT(A3T_bf, m0, n0, t, sm);
    } else {
        gemm64_mfma(A2_bf, A2T_bf, m0, n0, t, sm);    // A4[m][n]
        epi_out_f32(A4f, m0, n0, t, sm);
        epi_out_bf(A4_bf, m0, n0, t, sm);
        epi_out_bfT(A4T_bf, m0, n0, t, sm);
    }
}

// ===========================================================================
// K3 (grid 64): B = A4·S with S = c5A+c6A2+c7A3+c8A4 formed in staging;
// epilogue: M1 = A + c2A2 + c3A3 + c4A4 + B  ->  M1T_bf (transposed)
// ===========================================================================
__global__ __launch_bounds__(256) void k_prep3(
    const float* __restrict__ A, const float* __restrict__ A2f,
    const float* __restrict__ A3f, const float* __restrict__ A4f,
    const unsigned short* __restrict__ A4_bf,
    const unsigned short* __restrict__ AT_bf,
    const unsigned short* __restrict__ A2T_bf,
    const unsigned short* __restrict__ A3T_bf,
    const unsigned short* __restrict__ A4T_bf,
    unsigned short* __restrict__ M1T_bf) {
    __shared__ SqSmem sm;
    const int b = blockIdx.x, t = threadIdx.x;
    const int m0 = (b >> 3) * 64, n0 = (b & 7) * 64;
    const int lane = t & 63, w = t >> 6, quad = lane >> 4, l16 = lane & 15;
    const int wm = (w & 1) * 32, wn = (w >> 1) * 32;
    f32x4 acc[2][2];
#pragma unroll
    for (int i = 0; i < 2; ++i)
#pragma unroll
        for (int j = 0; j < 2; ++j) acc[i][j] = (f32x4){0.f, 0.f, 0.f, 0.f};
    for (int kt = 0; kt < 8; ++kt) {
#pragma unroll
        for (int c = 0; c < 2; ++c) {
            int idx = c * 256 + t, row = idx >> 3, cc = idx & 7;
            int ccs = cc ^ (row & 7);
            *(us8*)&sm.s.A[row * 64 + ccs * 8] =
                *(const us8*)&A4_bf[(size_t)(m0 + row) * 512 + kt * 64 + cc * 8];
            size_t go = (size_t)(n0 + row) * 512 + kt * 64 + cc * 8;
            us8 p1 = *(const us8*)&AT_bf[go];
            us8 p2 = *(const us8*)&A2T_bf[go];
            us8 p3 = *(const us8*)&A3T_bf[go];
            us8 p4 = *(const us8*)&A4T_bf[go];
            us8 o;
#pragma unroll
            for (int j = 0; j < 8; ++j)
                o[j] = f2bf(C5 * bf2f(p1[j]) + C6 * bf2f(p2[j]) +
                            C7 * bf2f(p3[j]) + C8 * bf2f(p4[j]));
            *(us8*)&sm.s.B[row * 64 + ccs * 8] = o;
        }
        __syncthreads();
#pragma unroll
        for (int ks = 0; ks < 2; ++ks) {
            bf16x8 af[2], bfr[2];
#pragma unroll
            for (int i = 0; i < 2; ++i) {
                int ra = wm + i * 16 + l16, ca = (ks * 4 + quad) ^ (ra & 7);
                af[i] = *(const bf16x8*)&sm.s.A[ra * 64 + ca * 8];
                int rb = wn + i * 16 + l16, cb = (ks * 4 + quad) ^ (rb & 7);
                bfr[i] = *(const bf16x8*)&sm.s.B[rb * 64 + cb * 8];
            }
#pragma unroll
            for (int i = 0; i < 2; ++i)
#pragma unroll
                for (int j = 0; j < 2; ++j)
                    acc[i][j] = __builtin_amdgcn_mfma_f32_16x16x32_bf16(
                        af[i], bfr[j], acc[i][j], 0, 0, 0);
        }
        __syncthreads();
    }
#pragma unroll
    for (int i = 0; i < 2; ++i)
#pragma unroll
        for (int j = 0; j < 2; ++j)
#pragma unroll
            for (int rr = 0; rr < 4; ++rr)
                sm.epi[(wm + i * 16 + quad * 4 + rr) * 68 + wn + j * 16 + l16] =
                    acc[i][j][rr];
    __syncthreads();
    // M1 = A + C2*A2 + C3*A3 + C4*A4 + B   (fp32, per-thread own elements)
    {
        const int r = t >> 2, cq = t & 3;
#pragma unroll
        for (int u = 0; u < 4; ++u) {
            size_t go = (size_t)(m0 + r) * 512 + n0 + cq * 16 + u * 4;
            float4 a1 = *(const float4*)&A[go];
            float4 a2 = *(const float4*)&A2f[go];
            float4 a3 = *(const float4*)&A3f[go];
            float4 a4 = *(const float4*)&A4f[go];
            int e = r * 68 + cq * 16 + u * 4;
            sm.epi[e + 0] = a1.x + C2 * a2.x + C3 * a3.x + C4 * a4.x + sm.epi[e + 0];
            sm.epi[e + 1] = a1.y + C2 * a2.y + C3 * a3.y + C4 * a4.y + sm.epi[e + 1];
            sm.epi[e + 2] = a1.z + C2 * a2.z + C3 * a3.z + C4 * a4.z + sm.epi[e + 2];
            sm.epi[e + 3] = a1.w + C2 * a2.w + C3 * a3.w + C4 * a4.w + sm.epi[e + 3];
        }
    }
    __syncthreads();
    epi_out_bfT(M1T_bf, m0, n0, t, sm);
}

// ===========================================================================
// K4 (grid 256): w1f = bf16(W1 + W1_bf·M1)  — proven round-3 fold
// ===========================================================================
__global__ __launch_bounds__(256) void k_fold(
    const unsigned short* __restrict__ w1_bf,
    const unsigned short* __restrict__ M1T, const float* __restrict__ W1,
    unsigned short* __restrict__ w1f) {
    __shared__ SqSmem sm;
    const int b = blockIdx.x, t = threadIdx.x;
    const int m0 = (b >> 3) * 64, n0 = (b & 7) * 64;
    gemm64_mfma(w1_bf, M1T, m0, n0, t, sm);
    const int r = t >> 2, cq = t & 3;
    float e2[16];
#pragma unroll
    for (int u = 0; u < 4; ++u) {
        float4 wv = *(const float4*)&W1[(size_t)(m0 + r) * 512 + n0 + cq * 16 + u * 4];
        e2[u * 4 + 0] = wv.x + sm.epi[r * 68 + cq * 16 + u * 4 + 0];
        e2[u * 4 + 1] = wv.y + sm.epi[r * 68 + cq * 16 + u * 4 + 1];
        e2[u * 4 + 2] = wv.z + sm.epi[r * 68 + cq * 16 + u * 4 + 2];
        e2[u * 4 + 3] = wv.w + sm.epi[r * 68 + cq * 16 + u * 4 + 3];
    }
    us8 h0, h1;
#pragma unroll
    for (int j = 0; j < 8; ++j) { h0[j] = f2bf(e2[j]); h1[j] = f2bf(e2[8 + j]); }
    *(us8*)&w1f[(size_t)(m0 + r) * 512 + n0 + cq * 16]     = h0;
    *(us8*)&w1f[(size_t)(m0 + r) * 512 + n0 + cq * 16 + 8] = h1;
}

// ===========================================================================
// K5: mlp v1 (proven round-3) — only change: launch_bounds min-waves 2 -> 4
// ===========================================================================
union SmemU {
    struct { unsigned short A[128 * 64]; unsigned short B[128 * 64]; } s; // 32 KB
    struct { unsigned short h[128 * 130]; float w2[DY * 132]; } e;        // 38.6 KB
};

__global__ __launch_bounds__(256, 4) void mlp_kernel(
    const unsigned short* __restrict__ x_bf,
    const unsigned short* __restrict__ w1f,
    const float* __restrict__ b1, const float* __restrict__ W2,
    float* __restrict__ y) {
    __shared__ SmemU sm;
    const int t    = threadIdx.x;
    const int lane = t & 63, w = t >> 6;
    const int quad = lane >> 4, l16 = lane & 15;
    const int wm = (w & 1) * 64, wn = (w >> 1) * 64;
    const int m0g = blockIdx.x * 128, n0g = blockIdx.y * 128;

    f32x4 acc[4][4];
#pragma unroll
    for (int i = 0; i < 4; ++i)
#pragma unroll
        for (int j = 0; j < 4; ++j) acc[i][j] = (f32x4){0.f, 0.f, 0.f, 0.f};

    for (int kt = 0; kt < 8; ++kt) {
#pragma unroll
        for (int c = 0; c < 4; ++c) {
            int idx = c * 256 + t;
            int row = idx >> 3, cc = idx & 7;
            int ccs = cc ^ (row & 7);
            us8 va = *(const us8*)&x_bf[(size_t)(m0g + row) * 512 + kt * 64 + cc * 8];
            *(us8*)&sm.s.A[row * 64 + ccs * 8] = va;
            us8 vb = *(const us8*)&w1f[(size_t)(n0g + row) * 512 + kt * 64 + cc * 8];
            *(us8*)&sm.s.B[row * 64 + ccs * 8] = vb;
        }
        __syncthreads();
#pragma unroll
        for (int ks = 0; ks < 2; ++ks) {
            bf16x8 af[4], bfr[4];
#pragma unroll
            for (int i = 0; i < 4; ++i) {
                int ra = wm + i * 16 + l16;
                int rb = wn + i * 16 + l16;
                int ca = (ks * 4 + quad) ^ (ra & 7);
                int cb = (ks * 4 + quad) ^ (rb & 7);
                af[i]  = *(const bf16x8*)&sm.s.A[ra * 64 + ca * 8];
                bfr[i] = *(const bf16x8*)&sm.s.B[rb * 64 + cb * 8];
            }
#pragma unroll
            for (int i = 0; i < 4; ++i)
#pragma unroll
                for (int j = 0; j < 4; ++j)
                    acc[i][j] = __builtin_amdgcn_mfma_f32_16x16x32_bf16(
                        af[i], bfr[j], acc[i][j], 0, 0, 0);
        }
        __syncthreads();
    }

    float bias[4];
#pragma unroll
    for (int j = 0; j < 4; ++j) bias[j] = b1[n0g + wn + j * 16 + l16];
#pragma unroll
    for (int i = 0; i < 4; ++i)
#pragma unroll
        for (int j = 0; j < 4; ++j)
#pragma unroll
            for (int r = 0; r < 4; ++r) {
                float h = acc[i][j][r] + bias[j];
                h = h > 0.f ? h : 0.f;
                sm.e.h[(wn + j * 16 + l16) * 130 + (wm + i * 16 + quad * 4 + r)] = f2bf(h);
            }
    for (int i = t; i < DY * 128; i += 256) {
        int d = i >> 7, n = i & 127;
        sm.e.w2[d * 132 + n] = W2[(size_t)d * H_SZ + n0g + n];
    }
    __syncthreads();
    {
        int m = t >> 1, dg = t & 1;
        float s0 = 0.f, s1 = 0.f, s2 = 0.f, s3 = 0.f, s4 = 0.f;
        const float* wrow = &sm.e.w2[dg * 5 * 132];
#pragma unroll 4
        for (int n = 0; n < 128; ++n) {
            float h = bf2f(sm.e.h[n * 130 + m]);
            s0 += h * wrow[n];
            s1 += h * wrow[132 + n];
            s2 += h * wrow[264 + n];
            s3 += h * wrow[396 + n];
            s4 += h * wrow[528 + n];
        }
        float* yp = &y[(size_t)(m0g + m) * DY + dg * 5];
        atomicAdd(yp + 0, s0);
        atomicAdd(yp + 1, s1);
        atomicAdd(yp + 2, s2);
        atomicAdd(yp + 3, s3);
        atomicAdd(yp + 4, s4);
    }
}

// ===========================================================================
extern "C" void kernel_launch(void* const* d_in, const int* in_sizes, int n_in,
                              void* d_out, int out_size, void* d_ws, size_t ws_size,
                              hipStream_t stream) {
    const float* x  = (const float*)d_in[0];
    const float* A  = (const float*)d_in[1];
    const float* W1 = (const float*)d_in[2];
    const float* b1 = (const float*)d_in[3];
    const float* W2 = (const float*)d_in[4];
    const float* b2 = (const float*)d_in[5];
    float* y = (float*)d_out;

    char* ws = (char*)d_ws;
    const size_t MB = 1u << 20, HMB = 512u * 1024;
    float* A2f = (float*)ws;                                   // 1 MB
    float* A3f = (float*)(ws + 1 * MB);                        // 1 MB
    float* A4f = (float*)(ws + 2 * MB);                        // 1 MB
    unsigned short* AT_bf  = (unsigned short*)(ws + 3 * MB);
    unsigned short* A2_bf  = (unsigned short*)(ws + 3 * MB + HMB);
    unsigned short* A2T_bf = (unsigned short*)(ws + 4 * MB);
    unsigned short* A3T_bf = (unsigned short*)(ws + 4 * MB + HMB);
    unsigned short* A4_bf  = (unsigned short*)(ws + 5 * MB);
    unsigned short* A4T_bf = (unsigned short*)(ws + 5 * MB + HMB);
    unsigned short* M1T_bf = (unsigned short*)(ws + 6 * MB);
    unsigned short* w1_bf  = (unsigned short*)(ws + 7 * MB);   // 2 MB
    unsigned short* w1f    = (unsigned short*)(ws + 9 * MB);   // 2 MB
    unsigned short* x_bf   = (unsigned short*)(ws + 11 * MB);  // 4 MB

    k_prep1<<<256, 256, 0, stream>>>(A, x, W1, b2, A2f, A2_bf, A2T_bf, AT_bf,
                                     x_bf, w1_bf, y);
    k_prep2<<<128, 256, 0, stream>>>(A2_bf, A2T_bf, AT_bf, A3f, A3T_bf, A4f,
                                     A4_bf, A4T_bf);
    k_prep3<<<64, 256, 0, stream>>>(A, A2f, A3f, A4f, A4_bf, AT_bf, A2T_bf,
                                    A3T_bf, A4T_bf, M1T_bf);
    k_fold<<<256, 256, 0, stream>>>(w1_bf, M1T_bf, W1, w1f);
    mlp_kernel<<<dim3(32, 16), dim3(256), 0, stream>>>(x_bf, w1f, b1, W2, y);
}